// Round 2
// baseline (351.168 us; speedup 1.0000x reference)
//
#include <hip/hip_runtime.h>
#include <hip/hip_bf16.h>

#define HW    12288
#define Wimg  192
#define Himg  64
#define Wpad  194
#define Ppad  12804   // 66*194

// ---------------------------------------------------------------------------
// K1: deformable gather.  grid = (192 pixel tiles, 4 channel blocks), 256 thr.
// Per tile: compute 9 taps x 4 (index,weight) pairs (channel-independent) into
// LDS, then each of 4 waves handles 16 channels x 64 pixels.
// ---------------------------------------------------------------------------
__global__ __launch_bounds__(256) void k_deform(
    const float* __restrict__ x,     // 256 x HW
    const float* __restrict__ xr,    // HW
    const float* __restrict__ rout,  // 256 x 9
    float* __restrict__ y0)          // 256 x HW (fp32)
{
    __shared__ int   s_idx[36][64];  // [k*4+j][pixel]
    __shared__ float s_w[36][64];
    __shared__ float s_r[64][9];     // this block's 64 channels x 9 taps

    const int tile = blockIdx.x;     // 0..191
    const int cblk = blockIdx.y;     // 0..3
    const int tid  = threadIdx.x;
    const int px0  = tile * 64;

    // stage range_out for this channel block
    for (int i = tid; i < 64 * 9; i += 256) {
        int cl = i / 9, k = i - cl * 9;
        s_r[cl][k] = rout[(cblk * 64 + cl) * 9 + k];
    }

    // per-(pixel,tap) bilinear pairs — replicate reference exactly (fp32)
    for (int item = tid; item < 64 * 9; item += 256) {
        int pl = item / 9, k = item - pl * 9;
        int gp = px0 + pl;
        int h = gp / Wimg, w = gp - h * Wimg;
        int xo = (k % 3) - 1;
        int yo = (k / 3) - 1;
        float off = 3.0f / (1.0f + expf(-xr[gp]));
        float ov  = off * (float)xo;          // fractional x part of offset_v
        int   iv  = yo * Wpad;                // integer y part of offset_v
        int   pre = (h + 1) * Wpad + (w + 1) + xo + iv;   // pre_v (int-exact)
        float after = (float)(pre + iv) + ov;             // pre_v + offset_v
        int fl = (int)floorf(ov);
        int ce = (int)ceilf(ov);
        int av_f  = min(max(pre + fl + iv, 0), Ppad - 1);
        int av_f1 = min(max(av_f + xo,    0), Ppad - 1);
        int av_c  = min(max(pre + ce + iv, 0), Ppad - 1);
        int av_c1 = min(max(av_c + xo,    0), Ppad - 1);
        float wf  = fabsf(after - (float)av_f);
        float wf1 = fabsf((float)av_f1 - after);
        float wc1 = fabsf(after - (float)av_c1);
        float wc  = fabsf((float)av_c - after);
        float s1 = wf  * (1.0f / Wpad);
        float s2 = wc1 * (1.0f / Wpad);
        int   idx4[4] = { av_f, av_f1, av_c1, av_c };
        float w4[4]   = { s1 * wf, s1 * wf1, s2 * wc1, s2 * wc };
        #pragma unroll
        for (int j = 0; j < 4; ++j) {
            int av = idx4[j];
            int r  = av / Wpad;
            int cc = av - r * Wpad;
            bool inb = (r >= 1) && (r <= Himg) && (cc >= 1) && (cc <= Wimg);
            s_idx[k * 4 + j][pl] = inb ? ((r - 1) * Wimg + (cc - 1)) : 0;
            s_w[k * 4 + j][pl]   = inb ? w4[j] : 0.0f;
        }
    }
    __syncthreads();

    const int pl    = tid & 63;   // pixel lane (wave = 64 consecutive pixels)
    const int clane = tid >> 6;   // 0..3
    const int gp    = px0 + pl;
    for (int i = 0; i < 16; ++i) {
        int cl = clane + 4 * i;             // local channel 0..63
        int c  = cblk * 64 + cl;
        const float* xc = x + (size_t)c * HW;
        float acc = 0.0f;
        #pragma unroll
        for (int k = 0; k < 9; ++k) {
            float part = 0.0f;
            #pragma unroll
            for (int j = 0; j < 4; ++j) {
                part += s_w[k * 4 + j][pl] * xc[s_idx[k * 4 + j][pl]];
            }
            acc += s_r[cl][k] * part;
        }
        y0[(size_t)c * HW + gp] = acc;
    }
}

// ---------------------------------------------------------------------------
// K2/K5/K8: pointwise GEMM  Z[128 x HW] = W[128 x CIN] * A[CIN x HW], fp32.
// grid = 192 (64-pixel tiles), 256 threads = 64 px lanes x 4 o-groups,
// 32 accumulators / thread.
// ---------------------------------------------------------------------------
template <int CIN>
__global__ __launch_bounds__(256) void k_pw(
    const float* __restrict__ A,
    const float* __restrict__ Wm,
    float* __restrict__ Z)
{
    __shared__ float s_w[32 * 128];  // [cc][o]
    const int tid = threadIdx.x;
    const int pl  = tid & 63;
    const int ob  = (tid >> 6) * 32;
    const int gp  = blockIdx.x * 64 + pl;

    float acc[32];
    #pragma unroll
    for (int i = 0; i < 32; ++i) acc[i] = 0.0f;

    for (int cb = 0; cb < CIN; cb += 32) {
        for (int li = tid; li < 4096; li += 256) {
            int o  = li >> 5;
            int cc = li & 31;
            s_w[cc * 128 + o] = Wm[o * CIN + cb + cc];
        }
        __syncthreads();
        for (int cc = 0; cc < 32; ++cc) {
            float v = A[(size_t)(cb + cc) * HW + gp];
            #pragma unroll
            for (int i = 0; i < 32; ++i)
                acc[i] += s_w[cc * 128 + ob + i] * v;
        }
        __syncthreads();
    }
    #pragma unroll
    for (int i = 0; i < 32; ++i)
        Z[(size_t)(ob + i) * HW + gp] = acc[i];
}

// ---------------------------------------------------------------------------
// K3/K6/K9: per-channel BN stats -> (scale, shift).  grid = 128 blocks.
// ---------------------------------------------------------------------------
__global__ __launch_bounds__(256) void k_stats(
    const float* __restrict__ Z,
    const float* __restrict__ g,
    const float* __restrict__ b,
    float* __restrict__ params)   // [c] -> scale, shift
{
    __shared__ float s_s[4], s_q[4];
    const int c   = blockIdx.x;
    const int tid = threadIdx.x;
    float s = 0.0f, q = 0.0f;
    for (int i = tid; i < HW; i += 256) {
        float v = Z[(size_t)c * HW + i];
        s += v;
        q += v * v;
    }
    #pragma unroll
    for (int off = 32; off > 0; off >>= 1) {
        s += __shfl_down(s, off, 64);
        q += __shfl_down(q, off, 64);
    }
    if ((tid & 63) == 0) { s_s[tid >> 6] = s; s_q[tid >> 6] = q; }
    __syncthreads();
    if (tid == 0) {
        s = s_s[0] + s_s[1] + s_s[2] + s_s[3];
        q = s_q[0] + s_q[1] + s_q[2] + s_q[3];
        float mu  = s * (1.0f / HW);
        float var = q * (1.0f / HW) - mu * mu;
        float sc  = g[c] * rsqrtf(var + 1e-5f);
        params[2 * c]     = sc;
        params[2 * c + 1] = b[c] - mu * sc;
    }
}

// ---------------------------------------------------------------------------
// K4/K7: fused BN+LeakyReLU then depthwise 3x3 (pad 1).  One thread / output.
// HW % 256 == 0 so every block is single-channel (uniform weight loads).
// ---------------------------------------------------------------------------
__global__ __launch_bounds__(256) void k_dw(
    const float* __restrict__ Z,
    const float* __restrict__ params,
    const float* __restrict__ dwgt,  // 128 x 9
    float* __restrict__ D)
{
    const int t = blockIdx.x * 256 + threadIdx.x;
    const int c = t / HW;
    const int p = t - c * HW;
    const int h = p / Wimg;
    const int w = p - h * Wimg;
    const float sc = params[2 * c];
    const float sh = params[2 * c + 1];
    float wk[9];
    #pragma unroll
    for (int k = 0; k < 9; ++k) wk[k] = dwgt[c * 9 + k];
    float acc = 0.0f;
    #pragma unroll
    for (int ky = 0; ky < 3; ++ky) {
        int hh = h + ky - 1;
        if (hh < 0 || hh >= Himg) continue;
        #pragma unroll
        for (int kx = 0; kx < 3; ++kx) {
            int ww = w + kx - 1;
            if (ww < 0 || ww >= Wimg) continue;
            float z = Z[(size_t)c * HW + hh * Wimg + ww];
            float y = z * sc + sh;
            y = (y >= 0.0f) ? y : 0.01f * y;
            acc += wk[ky * 3 + kx] * y;
        }
    }
    D[t] = acc;
}

// ---------------------------------------------------------------------------
// K10: final BN+LeakyReLU (fp32 out).
// ---------------------------------------------------------------------------
__global__ __launch_bounds__(256) void k_final(
    const float* __restrict__ Z,
    const float* __restrict__ params,
    float* __restrict__ out)
{
    const int t = blockIdx.x * 256 + threadIdx.x;
    const int c = t / HW;
    float v = Z[t] * params[2 * c] + params[2 * c + 1];
    v = (v >= 0.0f) ? v : 0.01f * v;
    out[t] = v;
}

// ---------------------------------------------------------------------------
extern "C" void kernel_launch(void* const* d_in, const int* in_sizes, int n_in,
                              void* d_out, int out_size, void* d_ws, size_t ws_size,
                              hipStream_t stream) {
    const float* x   = (const float*)d_in[0];
    const float* xr  = (const float*)d_in[1];
    const float* ro  = (const float*)d_in[2];
    const float* wr  = (const float*)d_in[3];
    const float* gr  = (const float*)d_in[4];
    const float* br  = (const float*)d_in[5];
    const float* dw1 = (const float*)d_in[6];
    const float* pw1 = (const float*)d_in[7];
    const float* g1  = (const float*)d_in[8];
    const float* b1  = (const float*)d_in[9];
    const float* dw2 = (const float*)d_in[10];
    const float* pw2 = (const float*)d_in[11];
    const float* g2  = (const float*)d_in[12];
    const float* b2  = (const float*)d_in[13];

    float* ws = (float*)d_ws;
    // buffer plan (floats):
    float* y0 = ws;                 // 3,145,728   (256 x HW)
    float* z1 = ws + 3145728;       // 1,572,864   (128 x HW)
    float* d1 = ws + 4718592;       // 1,572,864
    float* z2 = ws;                 // reuse y0 slot (y0 dead after K2)
    float* d2 = z1;                 // reuse z1 slot (z1 dead after K4)
    float* z3 = ws + 1572864;       // second half of y0 slot (no overlap w/ z2)
    float* p1 = ws + 6291456;       // 256
    float* p2 = p1 + 256;
    float* p3 = p2 + 256;
    float* out = (float*)d_out;

    k_deform<<<dim3(192, 4), 256, 0, stream>>>(x, xr, ro, y0);
    k_pw<256><<<192, 256, 0, stream>>>(y0, wr, z1);
    k_stats<<<128, 256, 0, stream>>>(z1, gr, br, p1);
    k_dw<<<6144, 256, 0, stream>>>(z1, p1, dw1, d1);
    k_pw<128><<<192, 256, 0, stream>>>(d1, pw1, z2);
    k_stats<<<128, 256, 0, stream>>>(z2, g1, b1, p2);
    k_dw<<<6144, 256, 0, stream>>>(z2, p2, dw2, d2);
    k_pw<128><<<192, 256, 0, stream>>>(d2, pw2, z3);
    k_stats<<<128, 256, 0, stream>>>(z3, g2, b2, p3);
    k_final<<<6144, 256, 0, stream>>>(z3, p3, out);
}

// Round 3
// 314.996 us; speedup vs baseline: 1.1148x; 1.1148x over previous
//
#include <hip/hip_runtime.h>
#include <hip/hip_bf16.h>

#define HW    12288
#define Wimg  192
#define Himg  64
#define Wpad  194
#define Ppad  12804   // 66*194

// ---------------------------------------------------------------------------
// K1: deformable gather.  grid = (192 pixel tiles, 4 channel blocks), 256 thr.
// ---------------------------------------------------------------------------
__global__ __launch_bounds__(256) void k_deform(
    const float* __restrict__ x,     // 256 x HW
    const float* __restrict__ xr,    // HW
    const float* __restrict__ rout,  // 256 x 9
    float* __restrict__ y0)          // 256 x HW (fp32)
{
    __shared__ int   s_idx[36][64];  // [k*4+j][pixel]
    __shared__ float s_w[36][64];
    __shared__ float s_r[64][9];     // this block's 64 channels x 9 taps

    const int tile = blockIdx.x;     // 0..191
    const int cblk = blockIdx.y;     // 0..3
    const int tid  = threadIdx.x;
    const int px0  = tile * 64;

    for (int i = tid; i < 64 * 9; i += 256) {
        int cl = i / 9, k = i - cl * 9;
        s_r[cl][k] = rout[(cblk * 64 + cl) * 9 + k];
    }

    for (int item = tid; item < 64 * 9; item += 256) {
        int pl = item / 9, k = item - pl * 9;
        int gp = px0 + pl;
        int h = gp / Wimg, w = gp - h * Wimg;
        int xo = (k % 3) - 1;
        int yo = (k / 3) - 1;
        float off = 3.0f / (1.0f + expf(-xr[gp]));
        float ov  = off * (float)xo;
        int   iv  = yo * Wpad;
        int   pre = (h + 1) * Wpad + (w + 1) + xo + iv;
        float after = (float)(pre + iv) + ov;
        int fl = (int)floorf(ov);
        int ce = (int)ceilf(ov);
        int av_f  = min(max(pre + fl + iv, 0), Ppad - 1);
        int av_f1 = min(max(av_f + xo,    0), Ppad - 1);
        int av_c  = min(max(pre + ce + iv, 0), Ppad - 1);
        int av_c1 = min(max(av_c + xo,    0), Ppad - 1);
        float wf  = fabsf(after - (float)av_f);
        float wf1 = fabsf((float)av_f1 - after);
        float wc1 = fabsf(after - (float)av_c1);
        float wc  = fabsf((float)av_c - after);
        float s1 = wf  * (1.0f / Wpad);
        float s2 = wc1 * (1.0f / Wpad);
        int   idx4[4] = { av_f, av_f1, av_c1, av_c };
        float w4[4]   = { s1 * wf, s1 * wf1, s2 * wc1, s2 * wc };
        #pragma unroll
        for (int j = 0; j < 4; ++j) {
            int av = idx4[j];
            int r  = av / Wpad;
            int cc = av - r * Wpad;
            bool inb = (r >= 1) && (r <= Himg) && (cc >= 1) && (cc <= Wimg);
            s_idx[k * 4 + j][pl] = inb ? ((r - 1) * Wimg + (cc - 1)) : 0;
            s_w[k * 4 + j][pl]   = inb ? w4[j] : 0.0f;
        }
    }
    __syncthreads();

    const int pl    = tid & 63;
    const int clane = tid >> 6;
    const int gp    = px0 + pl;
    for (int i = 0; i < 16; ++i) {
        int cl = clane + 4 * i;
        int c  = cblk * 64 + cl;
        const float* xc = x + (size_t)c * HW;
        float acc = 0.0f;
        #pragma unroll
        for (int k = 0; k < 9; ++k) {
            float part = 0.0f;
            #pragma unroll
            for (int j = 0; j < 4; ++j) {
                part += s_w[k * 4 + j][pl] * xc[s_idx[k * 4 + j][pl]];
            }
            acc += s_r[cl][k] * part;
        }
        y0[(size_t)c * HW + gp] = acc;
    }
}

// ---------------------------------------------------------------------------
// Pointwise GEMM, register-tiled:  Z[128 x HW] = W[128 x CIN] * A[CIN x HW].
// Block = 64 outs x 64 px, 256 threads, each a 4x4 (o,px) tile. Weights are
// pre-transposed (Wt[CIN][128]) so both LDS stagings are coalesced and
// conflict-free.  BN partial stats (sum, sumsq per channel) fused into the
// epilogue via atomicAdd.  grid = (192, 2).
// ---------------------------------------------------------------------------
template <int CIN>
__global__ __launch_bounds__(256) void k_pw(
    const float* __restrict__ A,     // CIN x HW
    const float* __restrict__ Wt,    // CIN x 128 (transposed weights)
    float* __restrict__ Z,           // 128 x HW
    float* __restrict__ psum)        // 128 x {sum, sumsq}
{
    __shared__ float s_a[16][64];
    __shared__ float s_w[16][64];
    const int tid = threadIdx.x;
    const int tx  = tid & 15;        // px group (4 px)
    const int ty  = tid >> 4;        // o group (4 outs)
    const int px0 = blockIdx.x * 64;
    const int o0  = blockIdx.y * 64;

    float acc[4][4];
    #pragma unroll
    for (int i = 0; i < 4; ++i)
        #pragma unroll
        for (int j = 0; j < 4; ++j) acc[i][j] = 0.0f;

    const int scc = tid >> 6;        // 0..3 (staging row)
    const int sp  = tid & 63;        // staging col

    for (int cb = 0; cb < CIN; cb += 16) {
        #pragma unroll
        for (int it = 0; it < 4; ++it)
            s_a[scc + 4 * it][sp] = A[(size_t)(cb + scc + 4 * it) * HW + px0 + sp];
        #pragma unroll
        for (int it = 0; it < 4; ++it)
            s_w[scc + 4 * it][sp] = Wt[(size_t)(cb + scc + 4 * it) * 128 + o0 + sp];
        __syncthreads();
        #pragma unroll
        for (int cc = 0; cc < 16; ++cc) {
            float4 a4 = *(const float4*)&s_a[cc][tx * 4];
            float4 w4 = *(const float4*)&s_w[cc][ty * 4];
            acc[0][0] += w4.x * a4.x; acc[0][1] += w4.x * a4.y;
            acc[0][2] += w4.x * a4.z; acc[0][3] += w4.x * a4.w;
            acc[1][0] += w4.y * a4.x; acc[1][1] += w4.y * a4.y;
            acc[1][2] += w4.y * a4.z; acc[1][3] += w4.y * a4.w;
            acc[2][0] += w4.z * a4.x; acc[2][1] += w4.z * a4.y;
            acc[2][2] += w4.z * a4.z; acc[2][3] += w4.z * a4.w;
            acc[3][0] += w4.w * a4.x; acc[3][1] += w4.w * a4.y;
            acc[3][2] += w4.w * a4.z; acc[3][3] += w4.w * a4.w;
        }
        __syncthreads();
    }

    #pragma unroll
    for (int i = 0; i < 4; ++i) {
        float4 v = make_float4(acc[i][0], acc[i][1], acc[i][2], acc[i][3]);
        *(float4*)&Z[(size_t)(o0 + ty * 4 + i) * HW + px0 + tx * 4] = v;
    }

    // fused BN partial stats: reduce over the 16 tx-lanes of each ty group
    #pragma unroll
    for (int i = 0; i < 4; ++i) {
        float s = acc[i][0] + acc[i][1] + acc[i][2] + acc[i][3];
        float q = acc[i][0] * acc[i][0] + acc[i][1] * acc[i][1]
                + acc[i][2] * acc[i][2] + acc[i][3] * acc[i][3];
        #pragma unroll
        for (int off = 8; off > 0; off >>= 1) {
            s += __shfl_down(s, off, 16);
            q += __shfl_down(q, off, 16);
        }
        if (tx == 0) {
            atomicAdd(&psum[2 * (o0 + ty * 4 + i)],     s);
            atomicAdd(&psum[2 * (o0 + ty * 4 + i) + 1], q);
        }
    }
}

// ---------------------------------------------------------------------------
// Finalize BN params in place: (sum, sumsq) -> (scale, shift).  1 block.
// ---------------------------------------------------------------------------
__global__ void k_params(float* __restrict__ p,
                         const float* __restrict__ g,
                         const float* __restrict__ b)
{
    const int c = threadIdx.x;   // 128
    float s = p[2 * c], q = p[2 * c + 1];
    float mu  = s * (1.0f / HW);
    float var = q * (1.0f / HW) - mu * mu;
    float sc  = g[c] * rsqrtf(var + 1e-5f);
    p[2 * c]     = sc;
    p[2 * c + 1] = b[c] - mu * sc;
}

// ---------------------------------------------------------------------------
// Zero the three 256-float psum buffers (they sit contiguously).
// ---------------------------------------------------------------------------
__global__ void k_prep(float* __restrict__ p)
{
    for (int i = threadIdx.x; i < 768; i += 256) p[i] = 0.0f;
}

// ---------------------------------------------------------------------------
// Weight transpose: Wt[c][o] = W[o][c].  grid = 128 (one block per out row).
// ---------------------------------------------------------------------------
__global__ void k_tr(const float* __restrict__ W, float* __restrict__ Wt, int Cin)
{
    const int o = blockIdx.x;
    for (int c = threadIdx.x; c < Cin; c += 256)
        Wt[(size_t)c * 128 + o] = W[o * Cin + c];
}

// ---------------------------------------------------------------------------
// Fused BN+LeakyReLU then depthwise 3x3 (pad 1).  One thread / output.
// ---------------------------------------------------------------------------
__global__ __launch_bounds__(256) void k_dw(
    const float* __restrict__ Z,
    const float* __restrict__ params,
    const float* __restrict__ dwgt,  // 128 x 9
    float* __restrict__ D)
{
    const int t = blockIdx.x * 256 + threadIdx.x;
    const int c = t / HW;
    const int p = t - c * HW;
    const int h = p / Wimg;
    const int w = p - h * Wimg;
    const float sc = params[2 * c];
    const float sh = params[2 * c + 1];
    float wk[9];
    #pragma unroll
    for (int k = 0; k < 9; ++k) wk[k] = dwgt[c * 9 + k];
    float acc = 0.0f;
    #pragma unroll
    for (int ky = 0; ky < 3; ++ky) {
        int hh = h + ky - 1;
        if (hh < 0 || hh >= Himg) continue;
        #pragma unroll
        for (int kx = 0; kx < 3; ++kx) {
            int ww = w + kx - 1;
            if (ww < 0 || ww >= Wimg) continue;
            float z = Z[(size_t)c * HW + hh * Wimg + ww];
            float y = z * sc + sh;
            y = (y >= 0.0f) ? y : 0.01f * y;
            acc += wk[ky * 3 + kx] * y;
        }
    }
    D[t] = acc;
}

// ---------------------------------------------------------------------------
// Final BN+LeakyReLU (fp32 out).
// ---------------------------------------------------------------------------
__global__ __launch_bounds__(256) void k_final(
    const float* __restrict__ Z,
    const float* __restrict__ params,
    float* __restrict__ out)
{
    const int t = blockIdx.x * 256 + threadIdx.x;
    const int c = t / HW;
    float v = Z[t] * params[2 * c] + params[2 * c + 1];
    v = (v >= 0.0f) ? v : 0.01f * v;
    out[t] = v;
}

// ---------------------------------------------------------------------------
extern "C" void kernel_launch(void* const* d_in, const int* in_sizes, int n_in,
                              void* d_out, int out_size, void* d_ws, size_t ws_size,
                              hipStream_t stream) {
    const float* x   = (const float*)d_in[0];
    const float* xr  = (const float*)d_in[1];
    const float* ro  = (const float*)d_in[2];
    const float* wr  = (const float*)d_in[3];
    const float* gr  = (const float*)d_in[4];
    const float* br  = (const float*)d_in[5];
    const float* dw1 = (const float*)d_in[6];
    const float* pw1 = (const float*)d_in[7];
    const float* g1  = (const float*)d_in[8];
    const float* b1  = (const float*)d_in[9];
    const float* dw2 = (const float*)d_in[10];
    const float* pw2 = (const float*)d_in[11];
    const float* g2  = (const float*)d_in[12];
    const float* b2  = (const float*)d_in[13];

    float* ws = (float*)d_ws;
    // slots (floats): A = ws[0 .. 3145728)          (y0; later z2 = A_low, z3 = A_high)
    //                 B = ws[3145728 .. 4718592)    (z1; later pw1T scratch; later d2)
    //                 C = ws[4718592 .. 6291456)    (wrT scratch; later d1; later pw2T)
    //                 params = ws[6291456 .. 6292224)
    float* A  = ws;
    float* B  = ws + 3145728;
    float* C  = ws + 4718592;
    float* y0 = A;
    float* z1 = B;
    float* d1 = C;
    float* z2 = A;                   // first 1.5M of A
    float* d2 = B;
    float* z3 = A + 1572864;         // second half of A
    float* wrT  = C;                 // 32768 floats, dead before d1 written
    float* pw1T = B;                 // 16384 floats, staged after z1 is dead
    float* pw2T = C;                 // 16384 floats, staged after d1 is dead
    float* p1 = ws + 6291456;
    float* p2 = p1 + 256;
    float* p3 = p2 + 256;
    float* out = (float*)d_out;

    k_prep<<<1, 256, 0, stream>>>(p1);
    k_tr<<<128, 256, 0, stream>>>(wr, wrT, 256);
    k_deform<<<dim3(192, 4), 256, 0, stream>>>(x, xr, ro, y0);
    k_pw<256><<<dim3(192, 2), 256, 0, stream>>>(y0, wrT, z1, p1);
    k_params<<<1, 128, 0, stream>>>(p1, gr, br);
    k_dw<<<6144, 256, 0, stream>>>(z1, p1, dw1, d1);
    k_tr<<<128, 256, 0, stream>>>(pw1, pw1T, 128);      // z1 (B) now dead
    k_pw<128><<<dim3(192, 2), 256, 0, stream>>>(d1, pw1T, z2, p2);
    k_params<<<1, 128, 0, stream>>>(p2, g1, b1);
    k_dw<<<6144, 256, 0, stream>>>(z2, p2, dw2, d2);    // overwrites pw1T (dead)
    k_tr<<<128, 256, 0, stream>>>(pw2, pw2T, 128);      // d1 (C) now dead
    k_pw<128><<<dim3(192, 2), 256, 0, stream>>>(d2, pw2T, z3, p3);
    k_params<<<1, 128, 0, stream>>>(p3, g2, b2);
    k_final<<<6144, 256, 0, stream>>>(z3, p3, out);
}